// Round 3
// baseline (71.123 us; speedup 1.0000x reference)
//
#include <hip/hip_runtime.h>
#include <math.h>

// B=4096 rows, C=128. labels {0,1}. loss = bce + wlsep (see R0 derivation).
// R2 lesson: harness's 256MB d_ws poison fill (~40us @ 6.7TB/s) is in the timed
// loop and is the floor; our controllable part was ~20us of small-kernel +
// dispatch overhead. R3: single fused kernel (last-block-done pattern, agent-
// scope atomics for cross-XCD visibility) + 4-byte counter memset.

#define C_DIM 128
#define RPW   8      // rows per wave
#define TPB   256    // 4 waves per block -> 32 rows per block

__device__ __forceinline__ float neg_log_sigmoid(float z) {
    // -log_sigmoid(z) = max(-z,0) + log1p(exp(-|z|))   (stable)
    return fmaxf(-z, 0.0f) + log1pf(__expf(-fabsf(z)));
}

__global__ __launch_bounds__(TPB) void bce_wlsep_fused(
        const float* __restrict__ x, const int* __restrict__ t,
        float* __restrict__ part,            // [3 * 512] slots in d_ws
        unsigned int* __restrict__ counter,  // zeroed via memsetAsync
        float* __restrict__ out, int B, int nblocks, float inv_BC) {
    const int wave = threadIdx.x >> 6;
    const int lane = threadIdx.x & 63;
    const int row0 = (blockIdx.x * 4 + wave) * RPW;

    // ---- issue all global loads up front (16 loads in flight / lane) ----
    float2 xs[RPW]; int2 ts[RPW];
    #pragma unroll
    for (int k = 0; k < RPW; ++k) {
        const int r = row0 + k;
        if (r < B) {
            xs[k] = ((const float2*)(x + (size_t)r * C_DIM))[lane];
            ts[k] = ((const int2*)(t + (size_t)r * C_DIM))[lane];
        } else {
            xs[k] = make_float2(0.f, 0.f); ts[k] = make_int2(1, 1);
        }
    }

    float bce = 0.f, wl = 0.f, pos = 0.f;
    #pragma unroll
    for (int k = 0; k < RPW; ++k) {
        if (row0 + k >= B) break;   // wave-uniform
        const float x0 = xs[k].x, x1 = xs[k].y;
        const int   t0 = ts[k].x,  t1 = ts[k].y;

        bce += neg_log_sigmoid(t0 ? x0 : -x0) + neg_log_sigmoid(t1 ? x1 : -x1);

        // max over negatives (xor butterfly: every lane gets the result)
        float m = -INFINITY;
        if (t0 == 0) m = x0;
        if (t1 == 0) m = fmaxf(m, x1);
        #pragma unroll
        for (int off = 32; off; off >>= 1) m = fmaxf(m, __shfl_xor(m, off, 64));

        // T = sum over negatives of exp(x - m)
        float T = 0.f;
        if (t0 == 0) T += __expf(x0 - m);
        if (t1 == 0) T += __expf(x1 - m);
        #pragma unroll
        for (int off = 32; off; off >>= 1) T += __shfl_xor(T, off, 64);

        if (t0) {
            float a = m - x0;   // m=-inf (no negatives) -> contribution 0
            wl += (a > 0.f) ? a + __logf(T + __expf(-a)) : log1pf(T * __expf(a));
            pos += 1.f;
        }
        if (t1) {
            float a = m - x1;
            wl += (a > 0.f) ? a + __logf(T + __expf(-a)) : log1pf(T * __expf(a));
            pos += 1.f;
        }
    }

    // ---- wave reduce (xor butterfly) ----
    #pragma unroll
    for (int off = 32; off; off >>= 1) {
        bce += __shfl_xor(bce, off, 64);
        wl  += __shfl_xor(wl,  off, 64);
        pos += __shfl_xor(pos, off, 64);
    }

    // ---- block reduce across 4 waves ----
    __shared__ float s[3][4];
    __shared__ int is_last;
    if (lane == 0) { s[0][wave] = bce; s[1][wave] = wl; s[2][wave] = pos; }
    __syncthreads();
    if (threadIdx.x == 0) {
        float b = s[0][0] + s[0][1] + s[0][2] + s[0][3];
        float w = s[1][0] + s[1][1] + s[1][2] + s[1][3];
        float p = s[2][0] + s[2][1] + s[2][2] + s[2][3];
        // agent-scope stores: per-XCD L2s are not coherent for plain stores
        __hip_atomic_store(&part[0*512 + blockIdx.x], b, __ATOMIC_RELAXED, __HIP_MEMORY_SCOPE_AGENT);
        __hip_atomic_store(&part[1*512 + blockIdx.x], w, __ATOMIC_RELAXED, __HIP_MEMORY_SCOPE_AGENT);
        __hip_atomic_store(&part[2*512 + blockIdx.x], p, __ATOMIC_RELAXED, __HIP_MEMORY_SCOPE_AGENT);
        unsigned old = __hip_atomic_fetch_add(counter, 1u, __ATOMIC_ACQ_REL, __HIP_MEMORY_SCOPE_AGENT);
        is_last = (old == (unsigned)(nblocks - 1));
    }
    __syncthreads();

    // ---- last arriving block reduces all partials and writes the scalar ----
    if (is_last) {
        float b = 0.f, w = 0.f, p = 0.f;
        for (int i = threadIdx.x; i < nblocks; i += TPB) {
            b += __hip_atomic_load(&part[0*512 + i], __ATOMIC_RELAXED, __HIP_MEMORY_SCOPE_AGENT);
            w += __hip_atomic_load(&part[1*512 + i], __ATOMIC_RELAXED, __HIP_MEMORY_SCOPE_AGENT);
            p += __hip_atomic_load(&part[2*512 + i], __ATOMIC_RELAXED, __HIP_MEMORY_SCOPE_AGENT);
        }
        #pragma unroll
        for (int off = 32; off; off >>= 1) {
            b += __shfl_xor(b, off, 64);
            w += __shfl_xor(w, off, 64);
            p += __shfl_xor(p, off, 64);
        }
        __syncthreads();   // reuse s[] safely
        if (lane == 0) { s[0][wave] = b; s[1][wave] = w; s[2][wave] = p; }
        __syncthreads();
        if (threadIdx.x == 0) {
            float fb = s[0][0] + s[0][1] + s[0][2] + s[0][3];
            float fw = s[1][0] + s[1][1] + s[1][2] + s[1][3];
            float fp = s[2][0] + s[2][1] + s[2][2] + s[2][3];
            out[0] = fb * inv_BC + fw / fp;
        }
    }
}

extern "C" void kernel_launch(void* const* d_in, const int* in_sizes, int n_in,
                              void* d_out, int out_size, void* d_ws, size_t ws_size,
                              hipStream_t stream) {
    const float* x = (const float*)d_in[0];
    const int*   t = (const int*)d_in[1];
    float* out = (float*)d_out;

    float* part = (float*)d_ws;                       // 3 * 512 floats
    unsigned int* counter = (unsigned int*)((char*)d_ws + 3 * 512 * sizeof(float));

    const int total = in_sizes[0];
    const int B = total / C_DIM;
    const int blocks = (B + RPW * 4 - 1) / (RPW * 4); // 128 for B=4096

    hipMemsetAsync(counter, 0, sizeof(unsigned int), stream);
    bce_wlsep_fused<<<blocks, TPB, 0, stream>>>(x, t, part, counter, out,
                                                B, blocks, 1.0f / (float)total);
}

// Round 4
// 62.612 us; speedup vs baseline: 1.1359x; 1.1359x over previous
//
#include <hip/hip_runtime.h>
#include <math.h>

// B=4096 rows, C=128, labels {0,1}. loss = bce + wlsep (R0 derivation).
// R3 lesson: acq_rel agent-scope atomics => per-block L2 writeback/invalidate
// sequences => +8us. R4: SINGLE dispatch, no memset, no fences. Partials are
// self-validating u64 words (lo=bits(v), hi=~lo) written with RELAXED
// device-scope atomic stores; last-dispatched block spins until hi==~lo for
// every slot (poison 0xAA.. and zeros both fail the check => init-free).

#define C_DIM 128
#define RPW   4      // rows per wave
#define TPB   256    // 4 waves/block -> 16 rows/block -> 256 blocks at B=4096

typedef unsigned int u32;
typedef unsigned long long u64;

__device__ __forceinline__ float neg_log_sigmoid(float z) {
    // -log_sigmoid(z) = max(-z,0) + log1p(exp(-|z|))   (stable)
    return fmaxf(-z, 0.0f) + log1pf(__expf(-fabsf(z)));
}

__device__ __forceinline__ u64 pack_checked(float f) {
    u32 v = __float_as_uint(f);
    return (u64)v | ((u64)(~v) << 32);
}

__global__ __launch_bounds__(TPB) void bce_wlsep_onepass(
        const float* __restrict__ x, const int* __restrict__ t,
        u64* __restrict__ slots,      // [3 * nblocks] in d_ws, NOT initialized
        float* __restrict__ out, int B, int nblocks, float inv_BC) {
    const int wave = threadIdx.x >> 6;
    const int lane = threadIdx.x & 63;
    const int row0 = (blockIdx.x * 4 + wave) * RPW;

    // ---- prefetch all rows (8 loads in flight per lane) ----
    float2 xs[RPW]; int2 ts[RPW];
    #pragma unroll
    for (int k = 0; k < RPW; ++k) {
        const int r = row0 + k;
        if (r < B) {
            xs[k] = ((const float2*)(x + (size_t)r * C_DIM))[lane];
            ts[k] = ((const int2*)(t + (size_t)r * C_DIM))[lane];
        } else { xs[k] = make_float2(0.f, 0.f); ts[k] = make_int2(1, 1); }
    }

    float bce = 0.f, wl = 0.f, pos = 0.f;
    #pragma unroll
    for (int k = 0; k < RPW; ++k) {
        if (row0 + k >= B) break;   // wave-uniform
        const float x0 = xs[k].x, x1 = xs[k].y;
        const int   t0 = ts[k].x,  t1 = ts[k].y;

        bce += neg_log_sigmoid(t0 ? x0 : -x0) + neg_log_sigmoid(t1 ? x1 : -x1);

        float m = -INFINITY;                  // max over negatives
        if (!t0) m = x0;
        if (!t1) m = fmaxf(m, x1);
        #pragma unroll
        for (int off = 32; off; off >>= 1) m = fmaxf(m, __shfl_xor(m, off, 64));

        float T = 0.f;                        // sum over negatives of exp(x-m)
        if (!t0) T += __expf(x0 - m);
        if (!t1) T += __expf(x1 - m);
        #pragma unroll
        for (int off = 32; off; off >>= 1) T += __shfl_xor(T, off, 64);

        if (t0) {
            float a = m - x0;   // m=-inf (no negatives) -> lse contribution 0
            wl += (a > 0.f) ? a + __logf(T + __expf(-a)) : log1pf(T * __expf(a));
            pos += 1.f;
        }
        if (t1) {
            float a = m - x1;
            wl += (a > 0.f) ? a + __logf(T + __expf(-a)) : log1pf(T * __expf(a));
            pos += 1.f;
        }
    }

    // ---- wave + block reduce ----
    #pragma unroll
    for (int off = 32; off; off >>= 1) {
        bce += __shfl_xor(bce, off, 64);
        wl  += __shfl_xor(wl,  off, 64);
        pos += __shfl_xor(pos, off, 64);
    }
    __shared__ float s[3][4];
    if (lane == 0) { s[0][wave] = bce; s[1][wave] = wl; s[2][wave] = pos; }
    __syncthreads();
    if (threadIdx.x == 0) {
        float b = s[0][0] + s[0][1] + s[0][2] + s[0][3];
        float w = s[1][0] + s[1][1] + s[1][2] + s[1][3];
        float p = s[2][0] + s[2][1] + s[2][2] + s[2][3];
        // RELAXED device-scope atomic stores: coherent path, no L2 flush.
        // Value is its own done-flag (hi == ~lo).
        __hip_atomic_store(&slots[3*blockIdx.x+0], pack_checked(b), __ATOMIC_RELAXED, __HIP_MEMORY_SCOPE_AGENT);
        __hip_atomic_store(&slots[3*blockIdx.x+1], pack_checked(w), __ATOMIC_RELAXED, __HIP_MEMORY_SCOPE_AGENT);
        __hip_atomic_store(&slots[3*blockIdx.x+2], pack_checked(p), __ATOMIC_RELAXED, __HIP_MEMORY_SCOPE_AGENT);
    }

    // ---- only the last-dispatched block finalizes ----
    if (blockIdx.x != (unsigned)(nblocks - 1)) return;

    float fb = 0.f, fw = 0.f, fp = 0.f;
    for (int i = threadIdx.x; i < nblocks; i += TPB) {
        u64 v;
        do { v = __hip_atomic_load(&slots[3*i+0], __ATOMIC_RELAXED, __HIP_MEMORY_SCOPE_AGENT); }
        while ((u32)(v >> 32) != ~(u32)v);
        fb += __uint_as_float((u32)v);
        do { v = __hip_atomic_load(&slots[3*i+1], __ATOMIC_RELAXED, __HIP_MEMORY_SCOPE_AGENT); }
        while ((u32)(v >> 32) != ~(u32)v);
        fw += __uint_as_float((u32)v);
        do { v = __hip_atomic_load(&slots[3*i+2], __ATOMIC_RELAXED, __HIP_MEMORY_SCOPE_AGENT); }
        while ((u32)(v >> 32) != ~(u32)v);
        fp += __uint_as_float((u32)v);
    }
    #pragma unroll
    for (int off = 32; off; off >>= 1) {
        fb += __shfl_xor(fb, off, 64);
        fw += __shfl_xor(fw, off, 64);
        fp += __shfl_xor(fp, off, 64);
    }
    __syncthreads();                 // safe: full block is here
    if (lane == 0) { s[0][wave] = fb; s[1][wave] = fw; s[2][wave] = fp; }
    __syncthreads();
    if (threadIdx.x == 0) {
        float b = s[0][0] + s[0][1] + s[0][2] + s[0][3];
        float w = s[1][0] + s[1][1] + s[1][2] + s[1][3];
        float p = s[2][0] + s[2][1] + s[2][2] + s[2][3];
        out[0] = b * inv_BC + w / p;
    }
}

extern "C" void kernel_launch(void* const* d_in, const int* in_sizes, int n_in,
                              void* d_out, int out_size, void* d_ws, size_t ws_size,
                              hipStream_t stream) {
    const float* x = (const float*)d_in[0];
    const int*   t = (const int*)d_in[1];
    float* out = (float*)d_out;
    u64* slots = (u64*)d_ws;   // 3 * nblocks u64, init-free protocol

    const int total = in_sizes[0];
    const int B = total / C_DIM;
    const int blocks = (B + RPW * 4 - 1) / (RPW * 4);   // 256 at B=4096

    bce_wlsep_onepass<<<blocks, TPB, 0, stream>>>(x, t, slots, out,
                                                  B, blocks, 1.0f / (float)total);
}

// Round 5
// 58.977 us; speedup vs baseline: 1.2060x; 1.0616x over previous
//
#include <hip/hip_runtime.h>
#include <math.h>

// B=4096 rows, C=128, labels {0,1}. loss = bce + wlsep.
//   bce   = mean(-log_sigmoid(label ? x : -x)) = mean(softplus(label ? -x : x))
//   wlsep = (1/Npos) * sum_{j pos} log1p(sum_{i neg} exp(x_i - x_j))
//         = (1/Npos) * sum_{j pos} softplus(L - x_j),  L = m + log(T),
//           m = max_neg x_i, T = sum_neg exp(x_i - m)
// R4 lesson: graph replay amortizes dispatch cost; remaining slack is the
// kernel body (~12us). R5: float4 loads (2 rows per wave, 32-lane halves),
// row-level L = m + log T (1 exp + 1 log per positive), fast intrinsics.
// Init-free cross-block protocol unchanged (relaxed atomics, hi==~lo check).

#define C_DIM 128
#define TPB   256    // 4 waves/block; 4 rows/wave -> 16 rows/block -> 256 blocks

typedef unsigned int u32;
typedef unsigned long long u64;

__device__ __forceinline__ float softplus_fast(float z) {
    // log(1+exp(z)) = max(z,0) + log(1 + exp(-|z|)); exact 0 at z=-inf
    return fmaxf(z, 0.0f) + __logf(1.0f + __expf(-fabsf(z)));
}

__device__ __forceinline__ u64 pack_checked(float f) {
    u32 v = __float_as_uint(f);
    return (u64)v | ((u64)(~v) << 32);
}

__global__ __launch_bounds__(TPB) void bce_wlsep_onepass(
        const float* __restrict__ x, const int* __restrict__ t,
        u64* __restrict__ slots,      // [3 * nblocks] in d_ws, uninitialized
        float* __restrict__ out, int B, int nblocks, float inv_BC) {
    const int wave = threadIdx.x >> 6;
    const int lane = threadIdx.x & 63;
    const int half = lane >> 5;       // which row of the pair
    const int sub  = lane & 31;       // element group within the row
    const int base = (blockIdx.x * 4 + wave) * 4;   // 4 rows per wave

    const float4* xq = (const float4*)x;
    const int4*   tq = (const int4*)t;

    // ---- prefetch: 2 pair-iterations, 4 loads in flight per lane ----
    float4 xv[2]; int4 tv[2];
    #pragma unroll
    for (int it = 0; it < 2; ++it) {
        const int r = base + 2 * it + half;
        if (r < B) {
            xv[it] = xq[(size_t)r * (C_DIM / 4) + sub];
            tv[it] = tq[(size_t)r * (C_DIM / 4) + sub];
        } else {
            // neutral row: all "negatives" at -inf -> zero contribution
            xv[it] = make_float4(-INFINITY, -INFINITY, -INFINITY, -INFINITY);
            tv[it] = make_int4(0, 0, 0, 0);
        }
    }

    float bce = 0.f, wl = 0.f, pos = 0.f;
    #pragma unroll
    for (int it = 0; it < 2; ++it) {
        const float xe[4] = {xv[it].x, xv[it].y, xv[it].z, xv[it].w};
        const int   te[4] = {tv[it].x, tv[it].y, tv[it].z, tv[it].w};

        // bce + row max over negatives (local)
        float m = -INFINITY;
        #pragma unroll
        for (int e = 0; e < 4; ++e) {
            bce += softplus_fast(te[e] ? -xe[e] : xe[e]);
            if (!te[e]) m = fmaxf(m, xe[e]);
        }
        // butterfly max within the 32-lane half
        #pragma unroll
        for (int off = 16; off; off >>= 1) m = fmaxf(m, __shfl_xor(m, off, 64));

        // T = sum over negatives of exp(x - m)
        float T = 0.f;
        #pragma unroll
        for (int e = 0; e < 4; ++e)
            if (!te[e]) T += __expf(xe[e] - m);
        #pragma unroll
        for (int off = 16; off; off >>= 1) T += __shfl_xor(T, off, 64);

        // L = m + log(T); no negatives -> L = -inf -> softplus(-inf) = 0
        const float L = m + __logf(T);
        #pragma unroll
        for (int e = 0; e < 4; ++e) {
            if (te[e]) { wl += softplus_fast(L - xe[e]); pos += 1.f; }
        }
    }

    // ---- full-wave reduce (sums both halves = both rows) ----
    #pragma unroll
    for (int off = 32; off; off >>= 1) {
        bce += __shfl_xor(bce, off, 64);
        wl  += __shfl_xor(wl,  off, 64);
        pos += __shfl_xor(pos, off, 64);
    }

    // ---- block reduce across 4 waves ----
    __shared__ float s[3][4];
    if (lane == 0) { s[0][wave] = bce; s[1][wave] = wl; s[2][wave] = pos; }
    __syncthreads();
    if (threadIdx.x == 0) {
        float b = s[0][0] + s[0][1] + s[0][2] + s[0][3];
        float w = s[1][0] + s[1][1] + s[1][2] + s[1][3];
        float p = s[2][0] + s[2][1] + s[2][2] + s[2][3];
        __hip_atomic_store(&slots[3*blockIdx.x+0], pack_checked(b), __ATOMIC_RELAXED, __HIP_MEMORY_SCOPE_AGENT);
        __hip_atomic_store(&slots[3*blockIdx.x+1], pack_checked(w), __ATOMIC_RELAXED, __HIP_MEMORY_SCOPE_AGENT);
        __hip_atomic_store(&slots[3*blockIdx.x+2], pack_checked(p), __ATOMIC_RELAXED, __HIP_MEMORY_SCOPE_AGENT);
    }

    // ---- last-dispatched block finalizes ----
    if (blockIdx.x != (unsigned)(nblocks - 1)) return;

    float fb = 0.f, fw = 0.f, fp = 0.f;
    for (int i = threadIdx.x; i < nblocks; i += TPB) {
        u64 v;
        do { v = __hip_atomic_load(&slots[3*i+0], __ATOMIC_RELAXED, __HIP_MEMORY_SCOPE_AGENT); }
        while ((u32)(v >> 32) != ~(u32)v);
        fb += __uint_as_float((u32)v);
        do { v = __hip_atomic_load(&slots[3*i+1], __ATOMIC_RELAXED, __HIP_MEMORY_SCOPE_AGENT); }
        while ((u32)(v >> 32) != ~(u32)v);
        fw += __uint_as_float((u32)v);
        do { v = __hip_atomic_load(&slots[3*i+2], __ATOMIC_RELAXED, __HIP_MEMORY_SCOPE_AGENT); }
        while ((u32)(v >> 32) != ~(u32)v);
        fp += __uint_as_float((u32)v);
    }
    #pragma unroll
    for (int off = 32; off; off >>= 1) {
        fb += __shfl_xor(fb, off, 64);
        fw += __shfl_xor(fw, off, 64);
        fp += __shfl_xor(fp, off, 64);
    }
    __syncthreads();                 // whole block is here; reuse s[]
    if (lane == 0) { s[0][wave] = fb; s[1][wave] = fw; s[2][wave] = fp; }
    __syncthreads();
    if (threadIdx.x == 0) {
        float b = s[0][0] + s[0][1] + s[0][2] + s[0][3];
        float w = s[1][0] + s[1][1] + s[1][2] + s[1][3];
        float p = s[2][0] + s[2][1] + s[2][2] + s[2][3];
        out[0] = b * inv_BC + w / p;
    }
}

extern "C" void kernel_launch(void* const* d_in, const int* in_sizes, int n_in,
                              void* d_out, int out_size, void* d_ws, size_t ws_size,
                              hipStream_t stream) {
    const float* x = (const float*)d_in[0];
    const int*   t = (const int*)d_in[1];
    float* out = (float*)d_out;
    u64* slots = (u64*)d_ws;   // 3 * nblocks u64, init-free protocol

    const int total = in_sizes[0];
    const int B = total / C_DIM;
    const int blocks = (B + 15) / 16;   // 16 rows/block -> 256 at B=4096

    bce_wlsep_onepass<<<blocks, TPB, 0, stream>>>(x, t, slots, out,
                                                  B, blocks, 1.0f / (float)total);
}